// Round 2
// baseline (241.324 us; speedup 1.0000x reference)
//
#include <hip/hip_runtime.h>
#include <math.h>

// x: (16, 512, 512, 8) float32 NHWC. float4 granule index:
//   f4idx = ((n*512 + h)*512 + w)*2 + c4,  c4 in {0,1}
//
// v3: LDS-TILED STREAMING. R1 showed time invariant (84us) under a 3x
// occupancy change with all pipes <35% busy -> bound by per-wave exposed
// memory latency (10 serialized load->vmcnt->compute round trips). Fix:
// block stages its whole input tile (10 rows x 66 w x 2 c4 = 21.1 KB) as
// ONE dependency-free burst of 5 coalesced loads/thread (+40 halo f4),
// one __syncthreads(), then all window math from LDS via immediate-offset
// ds_read_b128. -inf halos in LDS kill every edge conditional in compute.

constexpr int Hdim = 512;
constexpr int Wdim = 512;
constexpr int ROW  = Wdim * 2;       // f4 stride between h rows
constexpr int TH   = 8;              // output rows per block
constexpr int TW   = 64;             // w positions per block
constexpr int LROWS = TH + 2;        // 10 staged rows (1 halo each side)
constexpr int LCOLS = TW * 2 + 4;    // 132 f4 per LDS row (2 halo f4 each side)

__device__ __forceinline__ float4 f4max(float4 a, float4 b) {
    return make_float4(fmaxf(a.x,b.x), fmaxf(a.y,b.y), fmaxf(a.z,b.z), fmaxf(a.w,b.w));
}

__global__ __launch_bounds__(256, 7) void nms_kernel(
    const float4* __restrict__ x,
    const unsigned char* __restrict__ mask_bytes,
    float4* __restrict__ out)
{
    __shared__ float4 lds[LROWS][LCOLS];   // 10*132*16 = 21120 B

    // ---- Decode 3x3 boolean mask robustly (int32 vs 1-byte bool layout).
    const int* mi = (const int*)mask_bytes;
    bool intlay = true;
    #pragma unroll
    for (int i = 0; i < 9; ++i) { int v = mi[i]; intlay = intlay && (v == 0 || v == 1); }
    bool m[9];
    #pragma unroll
    for (int i = 0; i < 9; ++i) m[i] = intlay ? (mi[i] != 0) : (mask_bytes[i] != 0);

    const float4 NEG = make_float4(-INFINITY, -INFINITY, -INFINITY, -INFINITY);

    int b  = blockIdx.x;
    int wg = b & 7;            // 8 w-groups of 64
    int hg = (b >> 3) & 63;    // 64 h-groups of 8
    int n  = b >> 9;
    int h0 = hg * TH;
    int w0 = wg * TW;
    int t  = threadIdx.x;

    // ---- Stage main tile: 10 rows x 128 f4, 5 loads/thread, coalesced,
    //      all issued as one burst (no dependent compute between them).
    int gb = ((n * Hdim + (h0 - 1)) * Wdim + w0) * 2;  // f4 of (row 0, col 0)
    #pragma unroll
    for (int i = 0; i < 5; ++i) {
        int idx = t + i * 256;
        int r = idx >> 7;          // 0..9
        int c = idx & 127;         // 0..127
        int h = h0 - 1 + r;
        float4 v = NEG;
        if (h >= 0 && h < Hdim)    // block/group-uniform branch
            v = x[gb + r * ROW + c];
        lds[r][2 + c] = v;
    }
    // ---- Halo cols: 10 rows x {w0-1, w0+64} x 2 c4 = 40 f4.
    if (t < 40) {
        int r    = t >> 2;
        int q    = t & 3;
        int side = q >> 1;         // 0 = low (w0-1), 1 = high (w0+64)
        int c4   = q & 1;
        int h    = h0 - 1 + r;
        int wgl  = side ? (w0 + TW) : (w0 - 1);
        float4 v = NEG;
        if (h >= 0 && h < Hdim && wgl >= 0 && wgl < Wdim)
            v = x[((n * Hdim + h) * Wdim + wgl) * 2 + c4];
        lds[r][side ? (2 + 2 * TW + c4) : c4] = v;
    }
    __syncthreads();

    // ---- Compute: thread owns 4 consecutive output rows at one (w, c4).
    int cidx = t & 127;            // main col 0..127
    int hb   = (t >> 7) * 4;       // first window-row (LDS index) 0 or 4
    int col  = 2 + cidx;
    int obase = ((n * Hdim + h0) * Wdim + w0) * 2 + cidx;

    float4 R0a = NEG, R0b = NEG, R1b = NEG, CTb = NEG;
    #pragma unroll
    for (int k = 0; k < 6; ++k) {
        int r = hb + k;
        float4 a  = lds[r][col - 2];
        float4 bb = lds[r][col];
        float4 cc = lds[r][col + 2];

        float4 R0 = NEG, R1 = NEG, R2 = NEG;
        if (m[0]) R0 = f4max(R0, a);
        if (m[1]) R0 = f4max(R0, bb);
        if (m[2]) R0 = f4max(R0, cc);
        if (m[3]) R1 = f4max(R1, a);
        if (m[4]) R1 = f4max(R1, bb);
        if (m[5]) R1 = f4max(R1, cc);
        if (m[6]) R2 = f4max(R2, a);
        if (m[7]) R2 = f4max(R2, bb);
        if (m[8]) R2 = f4max(R2, cc);

        if (k >= 2) {
            float4 mm  = f4max(f4max(R0a, R1b), R2);
            float4 ctr = CTb;
            float4 o;
            o.x = (ctr.x > mm.x) ? ctr.x : 0.0f;
            o.y = (ctr.y > mm.y) ? ctr.y : 0.0f;
            o.z = (ctr.z > mm.z) ? ctr.z : 0.0f;
            o.w = (ctr.w > mm.w) ? ctr.w : 0.0f;
            out[obase + (hb + k - 2) * ROW] = o;
        }
        R0a = R0b; R0b = R0; R1b = R1; CTb = bb;
    }
}

extern "C" void kernel_launch(void* const* d_in, const int* in_sizes, int n_in,
                              void* d_out, int out_size, void* d_ws, size_t ws_size,
                              hipStream_t stream) {
    const float4* x = (const float4*)d_in[0];
    const unsigned char* mask = (const unsigned char*)d_in[1];
    float4* out = (float4*)d_out;

    // 16 n x 64 hg x 8 wg = 8192 blocks, 256 threads each.
    int grid = 16 * (Hdim / TH) * (Wdim / TW);
    int block = 256;
    nms_kernel<<<grid, block, 0, stream>>>(x, mask, out);
}

// Round 4
// 234.925 us; speedup vs baseline: 1.0272x; 1.0272x over previous
//
#include <hip/hip_runtime.h>
#include <math.h>

// x: (16, 512, 512, 8) float32 NHWC. float4 granule index:
//   f4idx = ((n*512 + h)*512 + w)*2 + c4,  c4 in {0,1}
//
// v4b = v3 + NONTEMPORAL STORES (compile-fixed: builtin requires a native
// clang vector type, not HIP_vector_type<float,4>).
// R0-R2: three structurally different kernels (25%/69%/60% occupancy,
// 30 vs 5 loads/thread, reg vs LDS) all pin at 84-87us with every pipe
// <40% -> limit is shared state, not structure. Theory: 134MB input +
// 134MB freshly-dirty output = 268MB > 256MB LLC -> capacity thrash;
// demand fetches interleave with dirty writebacks -> ~2.5TB/s effective.
// Output is write-once: stream it past the caches, free the LLC for input.

constexpr int Hdim = 512;
constexpr int Wdim = 512;
constexpr int ROW  = Wdim * 2;       // f4 stride between h rows
constexpr int TH   = 8;              // output rows per block
constexpr int TW   = 64;             // w positions per block
constexpr int LROWS = TH + 2;        // 10 staged rows (1 halo each side)
constexpr int LCOLS = TW * 2 + 4;    // 132 f4 per LDS row (2 halo f4 each side)

typedef float floatx4 __attribute__((ext_vector_type(4)));

__device__ __forceinline__ float4 f4max(float4 a, float4 b) {
    return make_float4(fmaxf(a.x,b.x), fmaxf(a.y,b.y), fmaxf(a.z,b.z), fmaxf(a.w,b.w));
}

__device__ __forceinline__ void nt_store_f4(float4* p, float4 v) {
    floatx4 nv;
    nv.x = v.x; nv.y = v.y; nv.z = v.z; nv.w = v.w;
    __builtin_nontemporal_store(nv, reinterpret_cast<floatx4*>(p));
}

__global__ __launch_bounds__(256, 7) void nms_kernel(
    const float4* __restrict__ x,
    const unsigned char* __restrict__ mask_bytes,
    float4* __restrict__ out)
{
    __shared__ float4 lds[LROWS][LCOLS];   // 10*132*16 = 21120 B

    // ---- Decode 3x3 boolean mask robustly (int32 vs 1-byte bool layout).
    const int* mi = (const int*)mask_bytes;
    bool intlay = true;
    #pragma unroll
    for (int i = 0; i < 9; ++i) { int v = mi[i]; intlay = intlay && (v == 0 || v == 1); }
    bool m[9];
    #pragma unroll
    for (int i = 0; i < 9; ++i) m[i] = intlay ? (mi[i] != 0) : (mask_bytes[i] != 0);

    const float4 NEG = make_float4(-INFINITY, -INFINITY, -INFINITY, -INFINITY);

    int b  = blockIdx.x;
    int wg = b & 7;            // 8 w-groups of 64
    int hg = (b >> 3) & 63;    // 64 h-groups of 8
    int n  = b >> 9;
    int h0 = hg * TH;
    int w0 = wg * TW;
    int t  = threadIdx.x;

    // ---- Stage main tile: 10 rows x 128 f4, 5 loads/thread, coalesced,
    //      all issued as one burst (no dependent compute between them).
    int gb = ((n * Hdim + (h0 - 1)) * Wdim + w0) * 2;  // f4 of (row 0, col 0)
    #pragma unroll
    for (int i = 0; i < 5; ++i) {
        int idx = t + i * 256;
        int r = idx >> 7;          // 0..9
        int c = idx & 127;         // 0..127
        int h = h0 - 1 + r;
        float4 v = NEG;
        if (h >= 0 && h < Hdim)    // block/group-uniform branch
            v = x[gb + r * ROW + c];
        lds[r][2 + c] = v;
    }
    // ---- Halo cols: 10 rows x {w0-1, w0+64} x 2 c4 = 40 f4.
    if (t < 40) {
        int r    = t >> 2;
        int q    = t & 3;
        int side = q >> 1;         // 0 = low (w0-1), 1 = high (w0+64)
        int c4   = q & 1;
        int h    = h0 - 1 + r;
        int wgl  = side ? (w0 + TW) : (w0 - 1);
        float4 v = NEG;
        if (h >= 0 && h < Hdim && wgl >= 0 && wgl < Wdim)
            v = x[((n * Hdim + h) * Wdim + wgl) * 2 + c4];
        lds[r][side ? (2 + 2 * TW + c4) : c4] = v;
    }
    __syncthreads();

    // ---- Compute: thread owns 4 consecutive output rows at one (w, c4).
    int cidx = t & 127;            // main col 0..127
    int hb   = (t >> 7) * 4;       // first window-row (LDS index) 0 or 4
    int col  = 2 + cidx;
    int obase = ((n * Hdim + h0) * Wdim + w0) * 2 + cidx;

    float4 R0a = NEG, R0b = NEG, R1b = NEG, CTb = NEG;
    #pragma unroll
    for (int k = 0; k < 6; ++k) {
        int r = hb + k;
        float4 a  = lds[r][col - 2];
        float4 bb = lds[r][col];
        float4 cc = lds[r][col + 2];

        float4 R0 = NEG, R1 = NEG, R2 = NEG;
        if (m[0]) R0 = f4max(R0, a);
        if (m[1]) R0 = f4max(R0, bb);
        if (m[2]) R0 = f4max(R0, cc);
        if (m[3]) R1 = f4max(R1, a);
        if (m[4]) R1 = f4max(R1, bb);
        if (m[5]) R1 = f4max(R1, cc);
        if (m[6]) R2 = f4max(R2, a);
        if (m[7]) R2 = f4max(R2, bb);
        if (m[8]) R2 = f4max(R2, cc);

        if (k >= 2) {
            float4 mm  = f4max(f4max(R0a, R1b), R2);
            float4 ctr = CTb;
            float4 o;
            o.x = (ctr.x > mm.x) ? ctr.x : 0.0f;
            o.y = (ctr.y > mm.y) ? ctr.y : 0.0f;
            o.z = (ctr.z > mm.z) ? ctr.z : 0.0f;
            o.w = (ctr.w > mm.w) ? ctr.w : 0.0f;
            // Non-temporal: output is write-once, never re-read by this
            // kernel. Keep it OUT of L2/LLC so input stays resident.
            nt_store_f4(&out[obase + (hb + k - 2) * ROW], o);
        }
        R0a = R0b; R0b = R0; R1b = R1; CTb = bb;
    }
}

extern "C" void kernel_launch(void* const* d_in, const int* in_sizes, int n_in,
                              void* d_out, int out_size, void* d_ws, size_t ws_size,
                              hipStream_t stream) {
    const float4* x = (const float4*)d_in[0];
    const unsigned char* mask = (const unsigned char*)d_in[1];
    float4* out = (float4*)d_out;

    // 16 n x 64 hg x 8 wg = 8192 blocks, 256 threads each.
    int grid = 16 * (Hdim / TH) * (Wdim / TW);
    int block = 256;
    nms_kernel<<<grid, block, 0, stream>>>(x, mask, out);
}